// Round 1
// baseline (1198.725 us; speedup 1.0000x reference)
//
#include <hip/hip_runtime.h>

#define IN_DIM   33
#define HID      64
#define OUT_DIM  2
#define PRED_LEN 25
#define NB       1024
#define NP       22
#define NT       20
#define G4       256   // 4*HID
#define XPAD     36    // IN_DIM padded to multiple of 4
#define EPS      1e-5f

__device__ __forceinline__ float fast_rcp(float x) { return __builtin_amdgcn_rcpf(x); }
__device__ __forceinline__ float sigm(float x)     { return fast_rcp(1.0f + __expf(-x)); }
__device__ __forceinline__ float tanh_fast(float x){
    // tanh(x) = 1 - 2/(exp(2x)+1); rcp(inf)=0 handles saturation gracefully
    float e = __expf(2.0f * x);
    return 1.0f - 2.0f * fast_rcp(e + 1.0f);
}

__global__ __launch_bounds__(256) void nfl_fused(
    const float* __restrict__ x,
    const float* __restrict__ enc_Wih, const float* __restrict__ enc_Whh,
    const float* __restrict__ enc_bih, const float* __restrict__ enc_bhh,
    const float* __restrict__ q_W, const float* __restrict__ q_b,
    const float* __restrict__ k_W, const float* __restrict__ k_b,
    const float* __restrict__ v_W, const float* __restrict__ v_b,
    const float* __restrict__ ln_g, const float* __restrict__ ln_b,
    const float* __restrict__ dec_Wih, const float* __restrict__ dec_Whh,
    const float* __restrict__ dec_bih, const float* __restrict__ dec_bhh,
    const float* __restrict__ fc_W, const float* __restrict__ fc_b,
    float* __restrict__ out)
{
    __shared__ float sh_h[NP * HID];   // hidden state
    __shared__ float sh_c[NP * HID];   // cell state
    __shared__ float sh_g[NP * G4];    // gates; reused as Q|K|V|scores scratch
    __shared__ float sh_x[NP * XPAD];  // x_t staging; reused as decoder input

    const int tid = threadIdx.x;
    const int b   = blockIdx.x;
    const int g   = tid;               // gate row owned by this thread

    // ---- encoder weights row g into registers (zero-padded Wih) ----
    float wih[XPAD];
    #pragma unroll
    for (int k = 0; k < XPAD; k++) wih[k] = (k < IN_DIM) ? enc_Wih[g * IN_DIM + k] : 0.0f;
    float whh[HID];
    #pragma unroll
    for (int k = 0; k < HID; k++) whh[k] = enc_Whh[g * HID + k];
    const float bias_e = enc_bih[g] + enc_bhh[g];

    // zero h, c
    for (int i = tid; i < NP * HID; i += 256) { sh_h[i] = 0.0f; sh_c[i] = 0.0f; }
    __syncthreads();

    const float* xb = x + (size_t)b * NP * NT * IN_DIM;

    // =================== encoder: 20 LSTM steps ===================
    for (int t = 0; t < NT; t++) {
        // stage x_t (zero the pad lanes)
        for (int i = tid; i < NP * XPAD; i += 256) {
            int s = i / XPAD, d = i - s * XPAD;
            sh_x[i] = (d < IN_DIM) ? xb[(s * NT + t) * IN_DIM + d] : 0.0f;
        }
        __syncthreads();

        // gates[s][g] = b + x_t[s,:]·Wih[g,:] + h[s,:]·Whh[g,:]
        for (int s = 0; s < NP; s += 2) {
            float acc0 = bias_e, acc1 = bias_e;
            const float4* x4a = reinterpret_cast<const float4*>(sh_x + s * XPAD);
            const float4* x4b = reinterpret_cast<const float4*>(sh_x + (s + 1) * XPAD);
            #pragma unroll
            for (int k = 0; k < XPAD / 4; k++) {
                float4 a = x4a[k], c = x4b[k];
                acc0 = fmaf(a.x, wih[4*k+0], acc0); acc1 = fmaf(c.x, wih[4*k+0], acc1);
                acc0 = fmaf(a.y, wih[4*k+1], acc0); acc1 = fmaf(c.y, wih[4*k+1], acc1);
                acc0 = fmaf(a.z, wih[4*k+2], acc0); acc1 = fmaf(c.z, wih[4*k+2], acc1);
                acc0 = fmaf(a.w, wih[4*k+3], acc0); acc1 = fmaf(c.w, wih[4*k+3], acc1);
            }
            const float4* h4a = reinterpret_cast<const float4*>(sh_h + s * HID);
            const float4* h4b = reinterpret_cast<const float4*>(sh_h + (s + 1) * HID);
            #pragma unroll
            for (int k = 0; k < HID / 4; k++) {
                float4 a = h4a[k], c = h4b[k];
                acc0 = fmaf(a.x, whh[4*k+0], acc0); acc1 = fmaf(c.x, whh[4*k+0], acc1);
                acc0 = fmaf(a.y, whh[4*k+1], acc0); acc1 = fmaf(c.y, whh[4*k+1], acc1);
                acc0 = fmaf(a.z, whh[4*k+2], acc0); acc1 = fmaf(c.z, whh[4*k+2], acc1);
                acc0 = fmaf(a.w, whh[4*k+3], acc0); acc1 = fmaf(c.w, whh[4*k+3], acc1);
            }
            sh_g[s * G4 + g]       = acc0;
            sh_g[(s + 1) * G4 + g] = acc1;
        }
        __syncthreads();

        // nonlinearity: h,c update (i,f,g,o split)
        for (int i = tid; i < NP * HID; i += 256) {
            int s = i >> 6, j = i & 63;
            float gi = sh_g[s * G4 + j];
            float gf = sh_g[s * G4 + 64 + j];
            float gg = sh_g[s * G4 + 128 + j];
            float go = sh_g[s * G4 + 192 + j];
            float c = sigm(gf) * sh_c[i] + sigm(gi) * tanh_fast(gg);
            sh_c[i] = c;
            sh_h[i] = sigm(go) * tanh_fast(c);
        }
        __syncthreads();
    }

    // =================== attention over P positions ===================
    float* Qb = sh_g;                 // [NP][HID]
    float* Kb = sh_g + NP * HID;      // [NP][HID]
    float* Vb = sh_g + 2 * NP * HID;  // [NP][HID]
    float* Sc = sh_g + 3 * NP * HID;  // [NP][NP] (484 <= 1408 spare)

    for (int i = tid; i < 3 * NP * HID; i += 256) {
        int sel = i / (NP * HID);
        int e   = i - sel * (NP * HID);
        int s = e >> 6, j = e & 63;
        const float* W  = (sel == 0) ? q_W : (sel == 1) ? k_W : v_W;
        const float* bb = (sel == 0) ? q_b : (sel == 1) ? k_b : v_b;
        float acc = bb[j];
        #pragma unroll
        for (int k = 0; k < HID; k++) acc = fmaf(sh_h[s * HID + k], W[j * HID + k], acc);
        sh_g[i] = acc;
    }
    __syncthreads();

    // scores = QK^T / sqrt(HID)
    for (int i = tid; i < NP * NP; i += 256) {
        int p = i / NP, q = i - p * NP;
        float acc = 0.0f;
        #pragma unroll
        for (int k = 0; k < HID; k++) acc = fmaf(Qb[p * HID + k], Kb[q * HID + k], acc);
        Sc[i] = acc * 0.125f;
    }
    __syncthreads();

    // softmax per row
    if (tid < NP) {
        float m = -1e30f;
        for (int q = 0; q < NP; q++) m = fmaxf(m, Sc[tid * NP + q]);
        float sum = 0.0f;
        for (int q = 0; q < NP; q++) { float e = __expf(Sc[tid * NP + q] - m); Sc[tid * NP + q] = e; sum += e; }
        float inv = fast_rcp(sum);
        for (int q = 0; q < NP; q++) Sc[tid * NP + q] *= inv;
    }
    __syncthreads();

    // ctx + residual into Qb (Q dead)
    for (int i = tid; i < NP * HID; i += 256) {
        int s = i >> 6, j = i & 63;
        float acc = 0.0f;
        #pragma unroll
        for (int q = 0; q < NP; q++) acc = fmaf(Sc[s * NP + q], Vb[q * HID + j], acc);
        Qb[i] = sh_h[i] + acc;
    }
    __syncthreads();

    // layernorm per row -> sh_h (decoder h0); sh_c stays = encoder cn
    if (tid < NP) {
        float mu = 0.0f;
        for (int j = 0; j < HID; j++) mu += Qb[tid * HID + j];
        mu *= (1.0f / HID);
        float var = 0.0f;
        for (int j = 0; j < HID; j++) { float d = Qb[tid * HID + j] - mu; var += d * d; }
        var *= (1.0f / HID);
        float inv = rsqrtf(var + EPS);
        for (int j = 0; j < HID; j++)
            sh_h[tid * HID + j] = (Qb[tid * HID + j] - mu) * inv * ln_g[j] + ln_b[j];
    }
    // decoder initial input = x[b, p, T-1, 0:2]
    if (tid < NP * OUT_DIM) {
        int s = tid >> 1, o = tid & 1;
        sh_x[s * XPAD + o] = xb[(s * NT + (NT - 1)) * IN_DIM + o];
    }
    __syncthreads();

    // =================== decoder: 25 LSTM steps + FC ===================
    const float wdih0 = dec_Wih[g * OUT_DIM + 0];
    const float wdih1 = dec_Wih[g * OUT_DIM + 1];
    float wdhh[HID];
    #pragma unroll
    for (int k = 0; k < HID; k++) wdhh[k] = dec_Whh[g * HID + k];
    const float bias_d = dec_bih[g] + dec_bhh[g];
    float* outb = out + (size_t)b * NP * PRED_LEN * OUT_DIM;

    for (int t = 0; t < PRED_LEN; t++) {
        for (int s = 0; s < NP; s += 2) {
            float acc0 = bias_d, acc1 = bias_d;
            acc0 = fmaf(sh_x[s * XPAD + 0], wdih0, acc0);
            acc0 = fmaf(sh_x[s * XPAD + 1], wdih1, acc0);
            acc1 = fmaf(sh_x[(s + 1) * XPAD + 0], wdih0, acc1);
            acc1 = fmaf(sh_x[(s + 1) * XPAD + 1], wdih1, acc1);
            const float4* h4a = reinterpret_cast<const float4*>(sh_h + s * HID);
            const float4* h4b = reinterpret_cast<const float4*>(sh_h + (s + 1) * HID);
            #pragma unroll
            for (int k = 0; k < HID / 4; k++) {
                float4 a = h4a[k], c = h4b[k];
                acc0 = fmaf(a.x, wdhh[4*k+0], acc0); acc1 = fmaf(c.x, wdhh[4*k+0], acc1);
                acc0 = fmaf(a.y, wdhh[4*k+1], acc0); acc1 = fmaf(c.y, wdhh[4*k+1], acc1);
                acc0 = fmaf(a.z, wdhh[4*k+2], acc0); acc1 = fmaf(c.z, wdhh[4*k+2], acc1);
                acc0 = fmaf(a.w, wdhh[4*k+3], acc0); acc1 = fmaf(c.w, wdhh[4*k+3], acc1);
            }
            sh_g[s * G4 + g]       = acc0;
            sh_g[(s + 1) * G4 + g] = acc1;
        }
        __syncthreads();

        for (int i = tid; i < NP * HID; i += 256) {
            int s = i >> 6, j = i & 63;
            float gi = sh_g[s * G4 + j];
            float gf = sh_g[s * G4 + 64 + j];
            float gg = sh_g[s * G4 + 128 + j];
            float go = sh_g[s * G4 + 192 + j];
            float c = sigm(gf) * sh_c[i] + sigm(gi) * tanh_fast(gg);
            sh_c[i] = c;
            sh_h[i] = sigm(go) * tanh_fast(c);
        }
        __syncthreads();

        // pred = h @ fc_W^T + fc_b ; write out and feed back
        if (tid < NP * OUT_DIM) {
            int s = tid >> 1, o = tid & 1;
            float acc = fc_b[o];
            #pragma unroll
            for (int k = 0; k < HID; k++) acc = fmaf(sh_h[s * HID + k], fc_W[o * HID + k], acc);
            outb[(s * PRED_LEN + t) * OUT_DIM + o] = acc;
            sh_x[s * XPAD + o] = acc;
        }
        __syncthreads();
    }
}

extern "C" void kernel_launch(void* const* d_in, const int* in_sizes, int n_in,
                              void* d_out, int out_size, void* d_ws, size_t ws_size,
                              hipStream_t stream) {
    const float* x        = (const float*)d_in[0];
    const float* enc_Wih  = (const float*)d_in[1];
    const float* enc_Whh  = (const float*)d_in[2];
    const float* enc_bih  = (const float*)d_in[3];
    const float* enc_bhh  = (const float*)d_in[4];
    const float* q_W      = (const float*)d_in[5];
    const float* q_b      = (const float*)d_in[6];
    const float* k_W      = (const float*)d_in[7];
    const float* k_b      = (const float*)d_in[8];
    const float* v_W      = (const float*)d_in[9];
    const float* v_b      = (const float*)d_in[10];
    const float* ln_g     = (const float*)d_in[11];
    const float* ln_b     = (const float*)d_in[12];
    const float* dec_Wih  = (const float*)d_in[13];
    const float* dec_Whh  = (const float*)d_in[14];
    const float* dec_bih  = (const float*)d_in[15];
    const float* dec_bhh  = (const float*)d_in[16];
    const float* fc_W     = (const float*)d_in[17];
    const float* fc_b     = (const float*)d_in[18];
    float* out = (float*)d_out;

    nfl_fused<<<dim3(NB), dim3(256), 0, stream>>>(
        x, enc_Wih, enc_Whh, enc_bih, enc_bhh,
        q_W, q_b, k_W, k_b, v_W, v_b, ln_g, ln_b,
        dec_Wih, dec_Whh, dec_bih, dec_bhh, fc_W, fc_b, out);
}

// Round 2
// 388.325 us; speedup vs baseline: 3.0869x; 3.0869x over previous
//
#include <hip/hip_runtime.h>

typedef short short8 __attribute__((ext_vector_type(8)));
typedef float f32x4 __attribute__((ext_vector_type(4)));

#define IN_DIM   33
#define HID      64
#define OUT_DIM  2
#define PRED_LEN 25
#define NB       1024
#define NP       22
#define NT       20
#define EPS      1e-5f

// swizzled element index into a [32][128] bf16 LDS tile (row stride 256B):
// XOR k (element units) with (s&7)<<3 -> spreads stride-256B columns across banks,
// keeps 8-element (16B) alignment for ds_read_b128.
#define SWZ(s,k) (((s) << 7) + ((k) ^ (((s) & 7) << 3)))

__device__ __forceinline__ float fast_rcp(float x){ return __builtin_amdgcn_rcpf(x); }
__device__ __forceinline__ float sigm(float x){ return fast_rcp(1.0f + __expf(-x)); }
__device__ __forceinline__ float tanhf_(float x){ float e = __expf(2.0f*x); return 1.0f - 2.0f*fast_rcp(e + 1.0f); }
// round-to-nearest-even f32 -> bf16
__device__ __forceinline__ unsigned short bf_hi(float f){
    unsigned u = __float_as_uint(f);
    return (unsigned short)((u + 0x7fffu + ((u >> 16) & 1u)) >> 16);
}
__device__ __forceinline__ float bf_f(unsigned short h){ return __uint_as_float(((unsigned)h) << 16); }

__global__ __launch_bounds__(256, 2) void nfl_mfma(
    const float* __restrict__ x,
    const float* __restrict__ enc_Wih, const float* __restrict__ enc_Whh,
    const float* __restrict__ enc_bih, const float* __restrict__ enc_bhh,
    const float* __restrict__ q_W, const float* __restrict__ q_b,
    const float* __restrict__ k_W, const float* __restrict__ k_b,
    const float* __restrict__ v_W, const float* __restrict__ v_b,
    const float* __restrict__ ln_g, const float* __restrict__ ln_b,
    const float* __restrict__ dec_Wih, const float* __restrict__ dec_Whh,
    const float* __restrict__ dec_bih, const float* __restrict__ dec_bhh,
    const float* __restrict__ fc_W, const float* __restrict__ fc_b,
    float* __restrict__ out)
{
    // A operand (h | x) as split bf16, swizzled
    __shared__ unsigned short shA_hi[32*128];
    __shared__ unsigned short shA_lo[32*128];
    __shared__ float sh_f[32*66];    // fp32 h_T, then y (attention scratch)
    __shared__ float sh_q[32*66];
    __shared__ float sh_k[32*66];
    __shared__ float sh_v[32*66];
    __shared__ float sh_sc[22*24];
    __shared__ float sh_p0[32];
    __shared__ float sh_p1[32];
    __shared__ float sh_mu[22];
    __shared__ float sh_rs[22];

    const int tid  = threadIdx.x;
    const int w    = tid >> 6;        // wave id 0..3
    const int ln   = tid & 63;
    const int lo15 = ln & 15;
    const int qq   = ln >> 4;         // lane quarter 0..3
    const int jh   = 16*w + lo15;     // this lane's hidden column (0..63)
    const int b    = blockIdx.x;
    const float* xb = x + (size_t)b * NP*NT*IN_DIM;

    // zero A tile (covers h region, x padding cols 97..127, rows 22..31)
    for (int i = tid; i < 32*128; i += 256){ shA_hi[i] = 0; shA_lo[i] = 0; }

    // ---- encoder B fragments in registers (split bf16) ----
    // B[k][g] = enc_Whh[g][k] (k<64) | enc_Wih[g][k-64] (k-64<33) | 0
    // frag(nt,kt): lane -> col g = 16w+64nt+lo15, k = 32kt + 8qq + e
    short8 eBh[4][4], eBl[4][4];
    float bias_e[4];
    #pragma unroll
    for (int nt = 0; nt < 4; nt++){
        int g = 16*w + 64*nt + lo15;
        bias_e[nt] = enc_bih[g] + enc_bhh[g];
        #pragma unroll
        for (int kt = 0; kt < 4; kt++){
            #pragma unroll
            for (int e = 0; e < 8; e++){
                int k = 32*kt + 8*qq + e;
                float v;
                if (k < HID) v = enc_Whh[g*HID + k];
                else { int d = k - HID; v = (d < IN_DIM) ? enc_Wih[g*IN_DIM + d] : 0.0f; }
                unsigned short h = bf_hi(v); float hf = bf_f(h);
                eBh[nt][kt][e] = (short)h;
                eBl[nt][kt][e] = (short)bf_hi(v - hf);
            }
        }
    }

    float cst[2][4] = {{0,0,0,0},{0,0,0,0}};   // cell state, per-lane
    __syncthreads();

    // =================== encoder: 20 MFMA LSTM steps ===================
    for (int t = 0; t < NT; t++){
        // stage x_t into A cols 64..96 (split bf16, swizzled)
        for (int i = tid; i < NP*IN_DIM; i += 256){
            int s = i / IN_DIM, d = i - s*IN_DIM;
            float v = xb[(s*NT + t)*IN_DIM + d];
            unsigned short h = bf_hi(v); float hf = bf_f(h);
            int idx = SWZ(s, HID + d);
            shA_hi[idx] = h; shA_lo[idx] = bf_hi(v - hf);
        }
        __syncthreads();

        f32x4 acc[2][4];
        #pragma unroll
        for (int m = 0; m < 2; m++)
            #pragma unroll
            for (int nt = 0; nt < 4; nt++){
                float bb = bias_e[nt];
                acc[m][nt][0]=bb; acc[m][nt][1]=bb; acc[m][nt][2]=bb; acc[m][nt][3]=bb;
            }
        #pragma unroll
        for (int kt = 0; kt < 4; kt++){
            #pragma unroll
            for (int m = 0; m < 2; m++){
                int idx = SWZ(16*m + lo15, 32*kt + 8*qq);
                short8 ah = *reinterpret_cast<const short8*>(&shA_hi[idx]);
                short8 al = *reinterpret_cast<const short8*>(&shA_lo[idx]);
                #pragma unroll
                for (int nt = 0; nt < 4; nt++){
                    acc[m][nt] = __builtin_amdgcn_mfma_f32_16x16x32_bf16(ah, eBh[nt][kt], acc[m][nt], 0,0,0);
                    acc[m][nt] = __builtin_amdgcn_mfma_f32_16x16x32_bf16(al, eBh[nt][kt], acc[m][nt], 0,0,0);
                    acc[m][nt] = __builtin_amdgcn_mfma_f32_16x16x32_bf16(ah, eBl[nt][kt], acc[m][nt], 0,0,0);
                }
            }
        }
        __syncthreads();   // all A-reads done before h overwrite

        // nonlinearity fully in-register: acc[m][0..3] = (i,f,g,o) for (s, jh)
        #pragma unroll
        for (int m = 0; m < 2; m++){
            #pragma unroll
            for (int j = 0; j < 4; j++){
                float gi = acc[m][0][j], gf = acc[m][1][j], gg = acc[m][2][j], go = acc[m][3][j];
                float c = sigm(gf)*cst[m][j] + sigm(gi)*tanhf_(gg);
                cst[m][j] = c;
                float h = sigm(go)*tanhf_(c);
                int s = 16*m + 4*qq + j;
                unsigned short hh = bf_hi(h); float hf2 = bf_f(hh);
                int idx = SWZ(s, jh);
                shA_hi[idx] = hh; shA_lo[idx] = bf_hi(h - hf2);
                if (t == NT-1) sh_f[s*66 + jh] = h;   // fp32 last_hidden for attention
            }
        }
        __syncthreads();   // h visible before next step's MFMA (x-stage writes are disjoint cols)
    }

    // =================== attention: QKV via MFMA ===================
    {
        short8 qBh[3][2], qBl[3][2];
        float qb3[3];
        #pragma unroll
        for (int mat = 0; mat < 3; mat++){
            const float* W  = (mat==0) ? q_W : (mat==1) ? k_W : v_W;
            const float* bb = (mat==0) ? q_b : (mat==1) ? k_b : v_b;
            qb3[mat] = bb[jh];
            #pragma unroll
            for (int kt = 0; kt < 2; kt++){
                #pragma unroll
                for (int e = 0; e < 8; e++){
                    int k = 32*kt + 8*qq + e;
                    float v = W[jh*HID + k];
                    unsigned short h = bf_hi(v); float hf = bf_f(h);
                    qBh[mat][kt][e] = (short)h;
                    qBl[mat][kt][e] = (short)bf_hi(v - hf);
                }
            }
        }
        f32x4 qacc[3][2];
        #pragma unroll
        for (int mat = 0; mat < 3; mat++)
            #pragma unroll
            for (int m = 0; m < 2; m++){
                float bb = qb3[mat];
                qacc[mat][m][0]=bb; qacc[mat][m][1]=bb; qacc[mat][m][2]=bb; qacc[mat][m][3]=bb;
            }
        #pragma unroll
        for (int kt = 0; kt < 2; kt++){
            #pragma unroll
            for (int m = 0; m < 2; m++){
                int idx = SWZ(16*m + lo15, 32*kt + 8*qq);
                short8 ah = *reinterpret_cast<const short8*>(&shA_hi[idx]);
                short8 al = *reinterpret_cast<const short8*>(&shA_lo[idx]);
                #pragma unroll
                for (int mat = 0; mat < 3; mat++){
                    qacc[mat][m] = __builtin_amdgcn_mfma_f32_16x16x32_bf16(ah, qBh[mat][kt], qacc[mat][m], 0,0,0);
                    qacc[mat][m] = __builtin_amdgcn_mfma_f32_16x16x32_bf16(al, qBh[mat][kt], qacc[mat][m], 0,0,0);
                    qacc[mat][m] = __builtin_amdgcn_mfma_f32_16x16x32_bf16(ah, qBl[mat][kt], qacc[mat][m], 0,0,0);
                }
            }
        }
        #pragma unroll
        for (int mat = 0; mat < 3; mat++){
            float* dst = (mat==0) ? sh_q : (mat==1) ? sh_k : sh_v;
            #pragma unroll
            for (int m = 0; m < 2; m++)
                #pragma unroll
                for (int j = 0; j < 4; j++)
                    dst[(16*m + 4*qq + j)*66 + jh] = qacc[mat][m][j];
        }
    }
    __syncthreads();

    // scores = QK^T / 8
    for (int i = tid; i < NP*NP; i += 256){
        int p = i / NP, q = i - p*NP;
        float acc = 0.0f;
        #pragma unroll
        for (int k = 0; k < HID; k++) acc = fmaf(sh_q[p*66 + k], sh_k[q*66 + k], acc);
        sh_sc[p*24 + q] = acc * 0.125f;
    }
    __syncthreads();

    if (tid < NP){
        float m = -1e30f;
        for (int q = 0; q < NP; q++) m = fmaxf(m, sh_sc[tid*24 + q]);
        float sum = 0.0f;
        for (int q = 0; q < NP; q++){ float e = __expf(sh_sc[tid*24 + q] - m); sh_sc[tid*24 + q] = e; sum += e; }
        float inv = fast_rcp(sum);
        for (int q = 0; q < NP; q++) sh_sc[tid*24 + q] *= inv;
    }
    __syncthreads();

    // y = h + attn@V  (in place into sh_f)
    for (int i = tid; i < NP*HID; i += 256){
        int s = i >> 6, j = i & 63;
        float acc = 0.0f;
        #pragma unroll
        for (int q = 0; q < NP; q++) acc = fmaf(sh_sc[s*24 + q], sh_v[q*66 + j], acc);
        sh_f[s*66 + j] += acc;
    }
    __syncthreads();

    // layernorm stats
    if (tid < NP){
        float mu = 0.0f;
        for (int j = 0; j < HID; j++) mu += sh_f[tid*66 + j];
        mu *= (1.0f/HID);
        float var = 0.0f;
        for (int j = 0; j < HID; j++){ float d = sh_f[tid*66 + j] - mu; var += d*d; }
        sh_mu[tid] = mu;
        sh_rs[tid] = rsqrtf(var*(1.0f/HID) + EPS);
    }
    __syncthreads();

    // LN apply -> decoder h0 into shA (split bf16); decoder input init
    for (int i = tid; i < NP*HID; i += 256){
        int s = i >> 6, j = i & 63;
        float v = (sh_f[s*66 + j] - sh_mu[s]) * sh_rs[s] * ln_g[j] + ln_b[j];
        unsigned short h = bf_hi(v); float hf = bf_f(h);
        int idx = SWZ(s, j);
        shA_hi[idx] = h; shA_lo[idx] = bf_hi(v - hf);
    }
    if (tid < 32){
        float v0 = 0.0f, v1 = 0.0f;
        if (tid < NP){
            v0 = xb[(tid*NT + NT-1)*IN_DIM + 0];
            v1 = xb[(tid*NT + NT-1)*IN_DIM + 1];
        }
        sh_p0[tid] = v0; sh_p1[tid] = v1;
    }

    // ---- decoder B fragments + FC weights ----
    short8 dBh[4][2], dBl[4][2];
    float bias_d[4], wd0[4], wd1[4];
    #pragma unroll
    for (int nt = 0; nt < 4; nt++){
        int g = 16*w + 64*nt + lo15;
        bias_d[nt] = dec_bih[g] + dec_bhh[g];
        wd0[nt] = dec_Wih[g*OUT_DIM + 0];
        wd1[nt] = dec_Wih[g*OUT_DIM + 1];
        #pragma unroll
        for (int kt = 0; kt < 2; kt++){
            #pragma unroll
            for (int e = 0; e < 8; e++){
                int k = 32*kt + 8*qq + e;
                float v = dec_Whh[g*HID + k];
                unsigned short h = bf_hi(v); float hf = bf_f(h);
                dBh[nt][kt][e] = (short)h;
                dBl[nt][kt][e] = (short)bf_hi(v - hf);
            }
        }
    }
    const int fitem = tid >> 2, fq = tid & 3, fs = fitem >> 1, fo = fitem & 1;
    float fcw[16]; float fcb = 0.0f;
    if (tid < 176){
        #pragma unroll
        for (int jj = 0; jj < 16; jj++) fcw[jj] = fc_W[fo*HID + 16*fq + jj];
        fcb = fc_b[fo];
    }
    float* outb = out + (size_t)b * NP * PRED_LEN * OUT_DIM;
    __syncthreads();

    // =================== decoder: 25 MFMA LSTM steps + FC ===================
    for (int t = 0; t < PRED_LEN; t++){
        f32x4 acc[2][4];
        #pragma unroll
        for (int m = 0; m < 2; m++){
            #pragma unroll
            for (int j = 0; j < 4; j++){
                int s = 16*m + 4*qq + j;
                float p0 = sh_p0[s], p1 = sh_p1[s];
                #pragma unroll
                for (int nt = 0; nt < 4; nt++)
                    acc[m][nt][j] = bias_d[nt] + wd0[nt]*p0 + wd1[nt]*p1;
            }
        }
        #pragma unroll
        for (int kt = 0; kt < 2; kt++){
            #pragma unroll
            for (int m = 0; m < 2; m++){
                int idx = SWZ(16*m + lo15, 32*kt + 8*qq);
                short8 ah = *reinterpret_cast<const short8*>(&shA_hi[idx]);
                short8 al = *reinterpret_cast<const short8*>(&shA_lo[idx]);
                #pragma unroll
                for (int nt = 0; nt < 4; nt++){
                    acc[m][nt] = __builtin_amdgcn_mfma_f32_16x16x32_bf16(ah, dBh[nt][kt], acc[m][nt], 0,0,0);
                    acc[m][nt] = __builtin_amdgcn_mfma_f32_16x16x32_bf16(al, dBh[nt][kt], acc[m][nt], 0,0,0);
                    acc[m][nt] = __builtin_amdgcn_mfma_f32_16x16x32_bf16(ah, dBl[nt][kt], acc[m][nt], 0,0,0);
                }
            }
        }
        __syncthreads();   // A/p reads done before overwrite

        #pragma unroll
        for (int m = 0; m < 2; m++){
            #pragma unroll
            for (int j = 0; j < 4; j++){
                float gi = acc[m][0][j], gf = acc[m][1][j], gg = acc[m][2][j], go = acc[m][3][j];
                float c = sigm(gf)*cst[m][j] + sigm(gi)*tanhf_(gg);
                cst[m][j] = c;
                float h = sigm(go)*tanhf_(c);
                int s = 16*m + 4*qq + j;
                unsigned short hh = bf_hi(h); float hf2 = bf_f(hh);
                int idx = SWZ(s, jh);
                shA_hi[idx] = hh; shA_lo[idx] = bf_hi(h - hf2);
            }
        }
        __syncthreads();   // h visible for FC

        if (tid < 176){
            int idx0 = SWZ(fs, 16*fq);
            int idx1 = SWZ(fs, 16*fq + 8);
            short8 h0h = *reinterpret_cast<const short8*>(&shA_hi[idx0]);
            short8 h0l = *reinterpret_cast<const short8*>(&shA_lo[idx0]);
            short8 h1h = *reinterpret_cast<const short8*>(&shA_hi[idx1]);
            short8 h1l = *reinterpret_cast<const short8*>(&shA_lo[idx1]);
            float part = 0.0f;
            #pragma unroll
            for (int e = 0; e < 8; e++){
                part = fmaf(bf_f((unsigned short)h0h[e]) + bf_f((unsigned short)h0l[e]), fcw[e],     part);
                part = fmaf(bf_f((unsigned short)h1h[e]) + bf_f((unsigned short)h1l[e]), fcw[8 + e], part);
            }
            part += __shfl_xor(part, 1);
            part += __shfl_xor(part, 2);
            if (fq == 0){
                float pred = part + fcb;
                outb[(fs*PRED_LEN + t)*OUT_DIM + fo] = pred;
                if (fo == 0) sh_p0[fs] = pred; else sh_p1[fs] = pred;
            }
        }
        __syncthreads();   // sh_p ready for next step
    }
}

extern "C" void kernel_launch(void* const* d_in, const int* in_sizes, int n_in,
                              void* d_out, int out_size, void* d_ws, size_t ws_size,
                              hipStream_t stream) {
    const float* x        = (const float*)d_in[0];
    const float* enc_Wih  = (const float*)d_in[1];
    const float* enc_Whh  = (const float*)d_in[2];
    const float* enc_bih  = (const float*)d_in[3];
    const float* enc_bhh  = (const float*)d_in[4];
    const float* q_W      = (const float*)d_in[5];
    const float* q_b      = (const float*)d_in[6];
    const float* k_W      = (const float*)d_in[7];
    const float* k_b      = (const float*)d_in[8];
    const float* v_W      = (const float*)d_in[9];
    const float* v_b      = (const float*)d_in[10];
    const float* ln_g     = (const float*)d_in[11];
    const float* ln_b     = (const float*)d_in[12];
    const float* dec_Wih  = (const float*)d_in[13];
    const float* dec_Whh  = (const float*)d_in[14];
    const float* dec_bih  = (const float*)d_in[15];
    const float* dec_bhh  = (const float*)d_in[16];
    const float* fc_W     = (const float*)d_in[17];
    const float* fc_b     = (const float*)d_in[18];
    float* out = (float*)d_out;

    nfl_mfma<<<dim3(NB), dim3(256), 0, stream>>>(
        x, enc_Wih, enc_Whh, enc_bih, enc_bhh,
        q_W, q_b, k_W, k_b, v_W, v_b, ln_g, ln_b,
        dec_Wih, dec_Whh, dec_bih, dec_bhh, fc_W, fc_b, out);
}